// Round 2
// baseline (205.784 us; speedup 1.0000x reference)
//
#include <hip/hip_runtime.h>
#include <hip/hip_bf16.h>

typedef __bf16 bf16x8 __attribute__((ext_vector_type(8)));
typedef __bf16 bf16x4 __attribute__((ext_vector_type(4)));
typedef float  f32x16 __attribute__((ext_vector_type(16)));
typedef float  f32x4  __attribute__((ext_vector_type(4)));

static __device__ __forceinline__ f32x16 mfma32(bf16x8 a, bf16x8 b, f32x16 c) {
    return __builtin_amdgcn_mfma_f32_32x32x16_bf16(a, b, c, 0, 0, 0);
}

// ---------------------------------------------------------------------------
// Pack kernel: repack W1 (as W1^T A-fragments) and W2 (as B-fragments) to bf16
// W1p[e][nt][ks][lane][j] = W1[e][k][n], k = ks*16+(lane>>5)*8+j, n = nt*32+(lane&31)
// W2p[e][ot][ks][lane][j] = W2[e][n][o], n = ks*16+(lane>>5)*8+j, o = ot*32+(lane&31)
// ---------------------------------------------------------------------------
__global__ __launch_bounds__(256) void pack_kernel(
    const float* __restrict__ We1, const float* __restrict__ Ws1,
    const float* __restrict__ We2, const float* __restrict__ Ws2,
    __bf16* __restrict__ w1p, __bf16* __restrict__ w2p)
{
    int idx = blockIdx.x * 256 + threadIdx.x;   // 0..40959
    int which = idx / 20480;
    int tid = idx - which * 20480;
    int l  = tid & 63;
    int ks = (tid >> 6) & 7;
    int nt = (tid >> 9) & 3;
    int e  = tid >> 11;                          // 0..9 (8 routed + 2 shared)
    const float* src;
    __bf16* dst;
    if (which == 0) {
        src = (e < 8) ? (We1 + e * 16384) : (Ws1 + (e - 8) * 16384);
        dst = w1p;
    } else {
        src = (e < 8) ? (We2 + e * 16384) : (Ws2 + (e - 8) * 16384);
        dst = w2p;
    }
    int col  = nt * 32 + (l & 31);
    int krow = ks * 16 + (l >> 5) * 8;
    bf16x8 v;
    #pragma unroll
    for (int j = 0; j < 8; ++j)
        v[j] = (__bf16)src[(krow + j) * 128 + col];
    *(bf16x8*)(dst + (((e * 4 + nt) * 8 + ks) * 64 + l) * 8) = v;
}

// ---------------------------------------------------------------------------
// Router kernel — FP64 accumulation + FP64 softmax/mask so the gate>1/8 mask
// decision matches a float64 numpy golden reference bit-for-bit at decision
// level (gates cluster at 0.125 +- 0.01, right at the threshold).
// mg[tok][8] = masked, renormalized gates (stored fp32).
// ---------------------------------------------------------------------------
__global__ __launch_bounds__(256) void router_kernel(
    const float* __restrict__ x,
    const float* __restrict__ Wr1, const float* __restrict__ br1,
    const float* __restrict__ Wr2, const float* __restrict__ br2,
    float* __restrict__ mg)
{
    int tok = blockIdx.x * 256 + threadIdx.x;
    const float* xr = x + (size_t)tok * 128;
    double rf[16];
    #pragma unroll
    for (int r = 0; r < 16; ++r) rf[r] = (double)br1[r];
    #pragma unroll 4
    for (int k = 0; k < 128; ++k) {
        double xv = (double)xr[k];
        #pragma unroll
        for (int r = 0; r < 16; ++r)
            rf[r] = fma(xv, (double)Wr1[k * 16 + r], rf[r]);
    }
    #pragma unroll
    for (int r = 0; r < 16; ++r) rf[r] = rf[r] > 0.0 ? rf[r] : 0.0;
    double lg[8];
    #pragma unroll
    for (int j = 0; j < 8; ++j) lg[j] = (double)br2[j];
    #pragma unroll
    for (int r = 0; r < 16; ++r) {
        double rv = rf[r];
        #pragma unroll
        for (int j = 0; j < 8; ++j)
            lg[j] = fma(rv, (double)Wr2[r * 8 + j], lg[j]);
    }
    double mx = lg[0];
    #pragma unroll
    for (int j = 1; j < 8; ++j) mx = lg[j] > mx ? lg[j] : mx;
    double ex[8]; double s = 0.0;
    #pragma unroll
    for (int j = 0; j < 8; ++j) { ex[j] = exp(lg[j] - mx); s += ex[j]; }
    double mv[8]; double ms = 0.0;
    #pragma unroll
    for (int j = 0; j < 8; ++j) {
        double g = ex[j] / s;
        double m = (g > 0.125) ? g : 0.0;
        mv[j] = m; ms += m;
    }
    double inv = 1.0 / (ms + 1e-8);
    f32x4 o0, o1;
    o0[0]=(float)(mv[0]*inv); o0[1]=(float)(mv[1]*inv);
    o0[2]=(float)(mv[2]*inv); o0[3]=(float)(mv[3]*inv);
    o1[0]=(float)(mv[4]*inv); o1[1]=(float)(mv[5]*inv);
    o1[2]=(float)(mv[6]*inv); o1[3]=(float)(mv[7]*inv);
    f32x4* op = (f32x4*)(mg + (size_t)tok * 8);
    op[0] = o0; op[1] = o1;
}

// ---------------------------------------------------------------------------
// Main fused MoE kernel. 128 tokens per block, 256 threads (4 waves).
// Per expert: Ht = W1p(e) @ Xp  (32x32x16 MFMA, transposed so C-layout rows =
// HID -> vectorized ds_write into A-frag-packed Hp), gelu+gate fused at the
// write; then out_acc += Hp @ W2p(e) accumulated in registers across all 10
// experts. Final epilogue adds the be2/bs2 bias terms and stores FP32.
// ---------------------------------------------------------------------------
__global__ __launch_bounds__(256, 2) void moe_main_kernel(
    const float* __restrict__ x, const float* __restrict__ mg,
    const __bf16* __restrict__ w1p, const __bf16* __restrict__ w2p,
    const float* __restrict__ be1, const float* __restrict__ bs1,
    const float* __restrict__ be2, const float* __restrict__ bs2,
    float* __restrict__ out)
{
    __shared__ __align__(16) __bf16 Xp[16384];   // 32 KB: [mt4][ks8][lane64][j8]
    __shared__ __align__(16) __bf16 Hp[16384];   // 32 KB: same layout

    const int t    = threadIdx.x;
    const int lane = t & 63;
    const int wave = t >> 6;
    const int l31  = lane & 31;
    const int lh   = lane >> 5;
    const int tok0 = blockIdx.x * 128;
    const int ntp  = (wave & 1) * 2;   // HID-tile (GEMM1) / OUT-tile (GEMM2) pair base
    const int mtp  = (wave >> 1) * 2;  // token-tile pair base

    // ---- stage X tile (fp32 global -> bf16 MFMA-frag-packed LDS) ----
    #pragma unroll
    for (int i = 0; i < 8; ++i) {
        int g = i * 256 + t;
        int m = g >> 4;        // token row 0..127
        int c = g & 15;        // 8-float chunk 0..15
        const f32x4* srcp = (const f32x4*)(x + (size_t)(tok0 + m) * 128 + c * 8);
        f32x4 va = srcp[0], vb = srcp[1];
        bf16x8 v;
        v[0]=(__bf16)va[0]; v[1]=(__bf16)va[1]; v[2]=(__bf16)va[2]; v[3]=(__bf16)va[3];
        v[4]=(__bf16)vb[0]; v[5]=(__bf16)vb[1]; v[6]=(__bf16)vb[2]; v[7]=(__bf16)vb[3];
        *(bf16x8*)&Xp[(((m >> 5) * 8 + (c >> 1)) * 64 + (c & 1) * 32 + (m & 31)) * 8] = v;
    }
    __syncthreads();

    f32x16 acc[2][2];   // persistent out accumulator [token-tile][out-tile]
    #pragma unroll
    for (int i0 = 0; i0 < 2; ++i0)
        #pragma unroll
        for (int i1 = 0; i1 < 2; ++i1)
            #pragma unroll
            for (int i = 0; i < 16; ++i) acc[i0][i1][i] = 0.f;

    #pragma unroll 1
    for (int e = 0; e < 10; ++e) {
        // gates for this expert (1.0 for shared experts)
        float gate0 = 1.f, gate1 = 1.f;
        if (e < 8) {
            gate0 = mg[(size_t)(tok0 + (mtp + 0) * 32 + l31) * 8 + e];
            gate1 = mg[(size_t)(tok0 + (mtp + 1) * 32 + l31) * 8 + e];
        }
        const float* b1p = (e < 8) ? (be1 + e * 128) : (bs1 + (e - 8) * 128);

        // preload W1^T A-fragments into registers
        const __bf16* w1b = w1p + (size_t)e * 16384;
        bf16x8 wf[2][8];
        #pragma unroll
        for (int n2 = 0; n2 < 2; ++n2)
            #pragma unroll
            for (int ks = 0; ks < 8; ++ks)
                wf[n2][ks] = *(const bf16x8*)(w1b + (((ntp + n2) * 8 + ks) * 64 + lane) * 8);

        // GEMM1 (transposed): Ht[n][m] = sum_k W1[k][n] * X[m][k]
        f32x16 a1[2][2];
        #pragma unroll
        for (int i0 = 0; i0 < 2; ++i0)
            #pragma unroll
            for (int i1 = 0; i1 < 2; ++i1)
                #pragma unroll
                for (int i = 0; i < 16; ++i) a1[i0][i1][i] = 0.f;

        #pragma unroll
        for (int ks = 0; ks < 8; ++ks) {
            bf16x8 xb0 = *(const bf16x8*)&Xp[(((mtp + 0) * 8 + ks) * 64 + lane) * 8];
            bf16x8 xb1 = *(const bf16x8*)&Xp[(((mtp + 1) * 8 + ks) * 64 + lane) * 8];
            a1[0][0] = mfma32(wf[0][ks], xb0, a1[0][0]);
            a1[0][1] = mfma32(wf[0][ks], xb1, a1[0][1]);
            a1[1][0] = mfma32(wf[1][ks], xb0, a1[1][0]);
            a1[1][1] = mfma32(wf[1][ks], xb1, a1[1][1]);
        }
        __syncthreads();   // previous expert's GEMM2 done reading Hp

        // epilogue: + be1, gelu(tanh), * gate, -> bf16, write A-frag-packed Hp
        #pragma unroll
        for (int n2 = 0; n2 < 2; ++n2) {
            const int ntile = ntp + n2;
            #pragma unroll
            for (int m2 = 0; m2 < 2; ++m2) {
                const int mtile = mtp + m2;
                const float gv = (m2 == 0) ? gate0 : gate1;
                #pragma unroll
                for (int gq = 0; gq < 4; ++gq) {
                    int n0 = ntile * 32 + gq * 8 + lh * 4;   // 4 consecutive n
                    f32x4 b1v = *(const f32x4*)(b1p + n0);
                    bf16x4 hv;
                    #pragma unroll
                    for (int q = 0; q < 4; ++q) {
                        float v = a1[n2][m2][gq * 4 + q] + b1v[q];
                        // gelu_tanh(v) == v * sigmoid(1.5957691216*(v + 0.044715 v^3))
                        float u  = 1.5957691216f * fmaf(0.044715f * v, v * v, v);
                        float sg = 1.f / (1.f + __expf(-u));
                        hv[q] = (__bf16)(v * sg * gv);
                    }
                    *(bf16x4*)&Hp[((mtile * 8 + (n0 >> 4)) * 64 + ((n0 >> 3) & 1) * 32 + l31) * 8
                                  + (n0 & 7)] = hv;
                }
            }
        }
        __syncthreads();   // Hp ready

        // preload W2 B-fragments (reuse wf registers)
        const __bf16* w2b = w2p + (size_t)e * 16384;
        #pragma unroll
        for (int o2 = 0; o2 < 2; ++o2)
            #pragma unroll
            for (int ks = 0; ks < 8; ++ks)
                wf[o2][ks] = *(const bf16x8*)(w2b + (((ntp + o2) * 8 + ks) * 64 + lane) * 8);

        // GEMM2: acc[m][o] += (mg*gelu(H))[m][n] * W2[n][o]
        #pragma unroll
        for (int ks = 0; ks < 8; ++ks) {
            bf16x8 h0 = *(const bf16x8*)&Hp[(((mtp + 0) * 8 + ks) * 64 + lane) * 8];
            bf16x8 h1 = *(const bf16x8*)&Hp[(((mtp + 1) * 8 + ks) * 64 + lane) * 8];
            acc[0][0] = mfma32(h0, wf[0][ks], acc[0][0]);
            acc[0][1] = mfma32(h0, wf[1][ks], acc[0][1]);
            acc[1][0] = mfma32(h1, wf[0][ks], acc[1][0]);
            acc[1][1] = mfma32(h1, wf[1][ks], acc[1][1]);
        }
    }

    // ---- final epilogue: + sum_e mg[m][e]*be2[e][o] + sum_s bs2[s][o]; store fp32 ----
    float be2c[2][8], bs2c[2];
    #pragma unroll
    for (int o2 = 0; o2 < 2; ++o2) {
        int o = (ntp + o2) * 32 + l31;
        #pragma unroll
        for (int ee = 0; ee < 8; ++ee) be2c[o2][ee] = be2[ee * 128 + o];
        bs2c[o2] = bs2[o] + bs2[128 + o];
    }
    const float* mgb = mg + (size_t)tok0 * 8;
    #pragma unroll
    for (int m2 = 0; m2 < 2; ++m2) {
        int mtile = mtp + m2;
        #pragma unroll
        for (int rg = 0; rg < 16; ++rg) {
            int mloc = mtile * 32 + 4 * lh + (rg & 3) + 8 * (rg >> 2);
            f32x4 g0 = *(const f32x4*)&mgb[mloc * 8];
            f32x4 g1 = *(const f32x4*)&mgb[mloc * 8 + 4];
            #pragma unroll
            for (int o2 = 0; o2 < 2; ++o2) {
                float b = bs2c[o2];
                #pragma unroll
                for (int ee = 0; ee < 4; ++ee) b = fmaf(g0[ee], be2c[o2][ee], b);
                #pragma unroll
                for (int ee = 0; ee < 4; ++ee) b = fmaf(g1[ee], be2c[o2][4 + ee], b);
                out[(size_t)(tok0 + mloc) * 128 + (ntp + o2) * 32 + l31] =
                    acc[m2][o2][rg] + b;
            }
        }
    }
}

// ---------------------------------------------------------------------------
extern "C" void kernel_launch(void* const* d_in, const int* in_sizes, int n_in,
                              void* d_out, int out_size, void* d_ws, size_t ws_size,
                              hipStream_t stream)
{
    const float* x   = (const float*)d_in[0];
    const float* Wr1 = (const float*)d_in[1];
    const float* br1 = (const float*)d_in[2];
    const float* Wr2 = (const float*)d_in[3];
    const float* br2 = (const float*)d_in[4];
    const float* We1 = (const float*)d_in[5];
    const float* be1 = (const float*)d_in[6];
    const float* We2 = (const float*)d_in[7];
    const float* be2 = (const float*)d_in[8];
    const float* Ws1 = (const float*)d_in[9];
    const float* bs1 = (const float*)d_in[10];
    const float* Ws2 = (const float*)d_in[11];
    const float* bs2 = (const float*)d_in[12];

    // ws layout: [0,327680) W1 packed bf16; [327680,655360) W2 packed bf16;
    // [655360, 655360+2MB) router gates fp32
    __bf16* w1p = (__bf16*)d_ws;
    __bf16* w2p = (__bf16*)((char*)d_ws + 327680);
    float*  mg  = (float*)((char*)d_ws + 655360);

    pack_kernel<<<160, 256, 0, stream>>>(We1, Ws1, We2, Ws2, w1p, w2p);
    router_kernel<<<256, 256, 0, stream>>>(x, Wr1, br1, Wr2, br2, mg);
    moe_main_kernel<<<512, 256, 0, stream>>>(x, mg, w1p, w2p, be1, bs1, be2, bs2,
                                             (float*)d_out);
}

// Round 3
// 197.010 us; speedup vs baseline: 1.0445x; 1.0445x over previous
//
#include <hip/hip_runtime.h>
#include <hip/hip_bf16.h>

typedef __bf16 bf16x8 __attribute__((ext_vector_type(8)));
typedef float  f32x16 __attribute__((ext_vector_type(16)));
typedef float  f32x4  __attribute__((ext_vector_type(4)));
typedef float  f32x2  __attribute__((ext_vector_type(2)));

static __device__ __forceinline__ f32x16 mfma32(bf16x8 a, bf16x8 b, f32x16 c) {
    return __builtin_amdgcn_mfma_f32_32x32x16_bf16(a, b, c, 0, 0, 0);
}

// gelu-tanh via sigmoid with log2e folded in:
// gelu(h) = h * sigmoid(1.5957691216*(h + 0.044715 h^3))
//         = h / (1 + exp2(-h*(C1 + C2*h^2)))
#define GELU_C1 2.30220820f
#define GELU_C2 0.10294324f

// ---------------------------------------------------------------------------
// Pack kernel.
// W1p (K=144, bias folded as k=128 row):
//   w1p[((e*4+nt)*9+ks)*64 + l][j] = k<128 ? W1[e][k][n] : (k==128 ? b1[e][n] : 0)
//   with k = ks*16 + (l>>5)*8 + j, n = nt*32 + (l&31)
// W2p (sigma-permuted so GEMM1 output frags feed GEMM2 directly):
//   w2p[((e*4+ot)*8+ks)*64 + l][j] = W2[e][hid][o]
//   with hid = 16ks + 8*(j>>2) + 4*(l>>5) + (j&3), o = ot*32 + (l&31)
// ---------------------------------------------------------------------------
__global__ __launch_bounds__(256) void pack_kernel(
    const float* __restrict__ We1, const float* __restrict__ be1,
    const float* __restrict__ Ws1, const float* __restrict__ bs1,
    const float* __restrict__ We2, const float* __restrict__ Ws2,
    __bf16* __restrict__ w1p, __bf16* __restrict__ w2p)
{
    int tid = blockIdx.x * 256 + threadIdx.x;
    if (tid < 23040) {
        int l  = tid & 63;
        int ks = (tid >> 6) % 9;
        int nt = (tid / 576) & 3;
        int e  = tid / 2304;
        const float* src = (e < 8) ? (We1 + e * 16384) : (Ws1 + (e - 8) * 16384);
        const float* bia = (e < 8) ? (be1 + e * 128)   : (bs1 + (e - 8) * 128);
        int n = nt * 32 + (l & 31);
        int kb = ks * 16 + (l >> 5) * 8;
        bf16x8 v;
        #pragma unroll
        for (int j = 0; j < 8; ++j) {
            int k = kb + j;
            float f = (k < 128) ? src[k * 128 + n] : ((k == 128) ? bia[n] : 0.f);
            v[j] = (__bf16)f;
        }
        *(bf16x8*)(w1p + (size_t)tid * 8) = v;
    } else if (tid < 43520) {
        int t2 = tid - 23040;
        int l  = t2 & 63;
        int ks = (t2 >> 6) & 7;
        int ot = (t2 / 512) & 3;
        int e  = t2 / 2048;
        const float* src = (e < 8) ? (We2 + e * 16384) : (Ws2 + (e - 8) * 16384);
        int o  = ot * 32 + (l & 31);
        int lh = l >> 5;
        bf16x8 v;
        #pragma unroll
        for (int j = 0; j < 8; ++j) {
            int hid = 16 * ks + 8 * (j >> 2) + 4 * lh + (j & 3);
            v[j] = (__bf16)src[hid * 128 + o];
        }
        *(bf16x8*)(w2p + (size_t)t2 * 8) = v;
    }
}

// ---------------------------------------------------------------------------
// Router kernel — fp64 math (gate>1/8 decisions sit right at the threshold),
// now with coalesced x reads via an LDS-staged tile.
// One wave per block, 64 tokens per block.
// ---------------------------------------------------------------------------
__global__ __launch_bounds__(64) void router_kernel(
    const float* __restrict__ x,
    const float* __restrict__ Wr1, const float* __restrict__ br1,
    const float* __restrict__ Wr2, const float* __restrict__ br2,
    float* __restrict__ mg)
{
    __shared__ __align__(16) float xs[64 * 132];
    int t = threadIdx.x;
    size_t base = (size_t)blockIdx.x * 64 * 128;
    #pragma unroll 4
    for (int i = 0; i < 32; ++i) {
        int idx = i * 64 + t;             // f32x4 index into 64x128 tile
        f32x4 v = *(const f32x4*)(x + base + (size_t)idx * 4);
        int m = (idx * 4) >> 7;
        int c = (idx * 4) & 127;
        *(f32x4*)&xs[m * 132 + c] = v;
    }
    __syncthreads();

    const f32x4* xr = (const f32x4*)(xs + t * 132);
    double rf[16];
    #pragma unroll
    for (int r = 0; r < 16; ++r) rf[r] = (double)br1[r];
    for (int c = 0; c < 32; ++c) {
        f32x4 xv4 = xr[c];
        #pragma unroll
        for (int q = 0; q < 4; ++q) {
            double xv = (double)xv4[q];
            int k = c * 4 + q;
            #pragma unroll
            for (int r = 0; r < 16; ++r)
                rf[r] = fma(xv, (double)Wr1[k * 16 + r], rf[r]);
        }
    }
    #pragma unroll
    for (int r = 0; r < 16; ++r) rf[r] = rf[r] > 0.0 ? rf[r] : 0.0;
    double lg[8];
    #pragma unroll
    for (int j = 0; j < 8; ++j) lg[j] = (double)br2[j];
    #pragma unroll
    for (int r = 0; r < 16; ++r) {
        double rv = rf[r];
        #pragma unroll
        for (int j = 0; j < 8; ++j)
            lg[j] = fma(rv, (double)Wr2[r * 8 + j], lg[j]);
    }
    double mx = lg[0];
    #pragma unroll
    for (int j = 1; j < 8; ++j) mx = lg[j] > mx ? lg[j] : mx;
    double ex[8]; double s = 0.0;
    #pragma unroll
    for (int j = 0; j < 8; ++j) { ex[j] = exp(lg[j] - mx); s += ex[j]; }
    double mv[8]; double ms = 0.0;
    #pragma unroll
    for (int j = 0; j < 8; ++j) {
        double g = ex[j] / s;
        double m = (g > 0.125) ? g : 0.0;
        mv[j] = m; ms += m;
    }
    double inv = 1.0 / (ms + 1e-8);
    int tok = blockIdx.x * 64 + t;
    f32x4 o0, o1;
    o0[0]=(float)(mv[0]*inv); o0[1]=(float)(mv[1]*inv);
    o0[2]=(float)(mv[2]*inv); o0[3]=(float)(mv[3]*inv);
    o1[0]=(float)(mv[4]*inv); o1[1]=(float)(mv[5]*inv);
    o1[2]=(float)(mv[6]*inv); o1[3]=(float)(mv[7]*inv);
    f32x4* op = (f32x4*)(mg + (size_t)tok * 8);
    op[0] = o0; op[1] = o1;
}

// ---------------------------------------------------------------------------
// Main fused MoE kernel. 64 tokens per block, 4 waves.
// Wave (mt, h): GEMM1 (K=144, bias folded) for n-tiles {2h,2h+1} -> gelu+gate
// packed directly into GEMM2 A-frags (sigma-permuted W2 makes the transpose
// free) -> partial GEMM2 over ks {4h..4h+3}, all 4 out-tiles. No barriers in
// the expert loop; one cross-wave acc reduction at the end.
// ---------------------------------------------------------------------------
__global__ __launch_bounds__(256, 2) void moe_main_kernel(
    const float* __restrict__ x, const float* __restrict__ mg,
    const __bf16* __restrict__ w1p, const __bf16* __restrict__ w2p,
    const float* __restrict__ be2, const float* __restrict__ bs2,
    float* __restrict__ out)
{
    __shared__ __align__(16) char lds[32768];
    __bf16* Xp = (__bf16*)lds;      // 2 mt * 9 ks * 64 lanes * 8 = 18432 B
    float*  Red = (float*)lds;      // 8192 f32 = 32768 B (after final barrier)

    const int t    = threadIdx.x;
    const int lane = t & 63;
    const int wave = t >> 6;
    const int l31  = lane & 31;
    const int lh   = lane >> 5;
    const int mt   = wave >> 1;
    const int h    = wave & 1;
    const int tok0 = blockIdx.x * 64;

    // ---- stage X (k<128) as MFMA B-frags ----
    #pragma unroll
    for (int i = 0; i < 4; ++i) {
        int g = i * 256 + t;       // 8-element group id, 0..1023
        int m = g >> 4;            // token 0..63
        int c = g & 15;            // which 8-k chunk
        const f32x4* sp = (const f32x4*)(x + (size_t)(tok0 + m) * 128 + c * 8);
        f32x4 va = sp[0], vb = sp[1];
        bf16x8 v;
        v[0]=(__bf16)va[0]; v[1]=(__bf16)va[1]; v[2]=(__bf16)va[2]; v[3]=(__bf16)va[3];
        v[4]=(__bf16)vb[0]; v[5]=(__bf16)vb[1]; v[6]=(__bf16)vb[2]; v[7]=(__bf16)vb[3];
        *(bf16x8*)&Xp[(((m >> 5) * 9 + (c >> 1)) * 64 + (c & 1) * 32 + (m & 31)) * 8] = v;
    }
    // ks=8 bias column: k=128 -> 1.0, k=129..143 -> 0
    if (t < 128) {
        int mtx = t >> 6, l = t & 63;
        bf16x8 v;
        #pragma unroll
        for (int j = 0; j < 8; ++j) v[j] = (__bf16)0.f;
        if (l < 32) v[0] = (__bf16)1.0f;
        *(bf16x8*)&Xp[((mtx * 9 + 8) * 64 + l) * 8] = v;
    }
    __syncthreads();

    // ---- per-token gates (token = l31 within this wave's mt tile) ----
    const float* mgr = mg + (size_t)(tok0 + 32 * mt + l31) * 8;
    f32x4 ga4 = *(const f32x4*)mgr;
    f32x4 gb4 = *(const f32x4*)(mgr + 4);
    float gte[8] = {ga4[0], ga4[1], ga4[2], ga4[3], gb4[0], gb4[1], gb4[2], gb4[3]};

    f32x16 acc[4];
    #pragma unroll
    for (int ot = 0; ot < 4; ++ot)
        #pragma unroll
        for (int i = 0; i < 16; ++i) acc[ot][i] = 0.f;

    const bf16x8* w1v = (const bf16x8*)w1p;
    const bf16x8* w2v = (const bf16x8*)w2p;

    #pragma unroll 1
    for (int e = 0; e < 10; ++e) {
        // W1^T A-frags for n-tiles 2h, 2h+1 (9 ks each, bias row included)
        const bf16x8* wap = w1v + ((size_t)(e * 4 + 2 * h) * 9) * 64 + lane;
        bf16x8 wa[9], wb[9];
        #pragma unroll
        for (int ks = 0; ks < 9; ++ks) { wa[ks] = wap[ks * 64]; wb[ks] = wap[(9 + ks) * 64]; }

        f32x16 a1[2];
        #pragma unroll
        for (int n2 = 0; n2 < 2; ++n2)
            #pragma unroll
            for (int i = 0; i < 16; ++i) a1[n2][i] = 0.f;

        #pragma unroll
        for (int ks = 0; ks < 9; ++ks) {
            bf16x8 xb = *(const bf16x8*)&Xp[((mt * 9 + ks) * 64 + lane) * 8];
            a1[0] = mfma32(wa[ks], xb, a1[0]);
            a1[1] = mfma32(wb[ks], xb, a1[1]);
        }

        // W2 B-frags: (ot 0..3) x (ks = 4h + kq, kq 0..3)
        const bf16x8* wBp = w2v + ((size_t)(e * 4) * 8 + 4 * h) * 64 + lane;
        bf16x8 wB[4][4];
        #pragma unroll
        for (int ot = 0; ot < 4; ++ot)
            #pragma unroll
            for (int kq = 0; kq < 4; ++kq)
                wB[ot][kq] = wBp[(ot * 8 + kq) * 64];

        const float gv = (e < 8) ? gte[e] : 1.0f;

        // gelu + gate -> A-frags -> GEMM2 (sigma-permuted, no data movement)
        #pragma unroll
        for (int n2 = 0; n2 < 2; ++n2) {
            #pragma unroll
            for (int b = 0; b < 2; ++b) {
                bf16x8 fr;
                #pragma unroll
                for (int jp = 0; jp < 4; ++jp) {
                    f32x2 hh; hh[0] = a1[n2][8 * b + 2 * jp]; hh[1] = a1[n2][8 * b + 2 * jp + 1];
                    f32x2 tt = hh * hh;
                    f32x2 pp;
                    pp[0] = fmaf(tt[0], -GELU_C2, -GELU_C1);
                    pp[1] = fmaf(tt[1], -GELU_C2, -GELU_C1);
                    f32x2 mm = hh * pp;
                    float e0 = __builtin_amdgcn_exp2f(mm[0]);
                    float e1 = __builtin_amdgcn_exp2f(mm[1]);
                    float q0 = __builtin_amdgcn_rcpf(1.f + e0);
                    float q1 = __builtin_amdgcn_rcpf(1.f + e1);
                    f32x2 gg; gg[0] = hh[0] * q0 * gv; gg[1] = hh[1] * q1 * gv;
                    fr[2 * jp]     = (__bf16)gg[0];
                    fr[2 * jp + 1] = (__bf16)gg[1];
                }
                int kq = 2 * n2 + b;
                acc[0] = mfma32(fr, wB[0][kq], acc[0]);
                acc[1] = mfma32(fr, wB[1][kq], acc[1]);
                acc[2] = mfma32(fr, wB[2][kq], acc[2]);
                acc[3] = mfma32(fr, wB[3][kq], acc[3]);
            }
        }
    }

    __syncthreads();   // all waves done with Xp; Red overlay now safe
    if (h == 1) {
        #pragma unroll
        for (int ot = 0; ot < 4; ++ot)
            #pragma unroll
            for (int r = 0; r < 16; ++r)
                Red[((mt * 4 + ot) * 16 + r) * 64 + lane] = acc[ot][r];
    }
    __syncthreads();
    if (h == 0) {
        float be2c[4][8], bsc[4];
        #pragma unroll
        for (int ot = 0; ot < 4; ++ot) {
            int o = 32 * ot + l31;
            bsc[ot] = bs2[o] + bs2[128 + o];
            #pragma unroll
            for (int ee = 0; ee < 8; ++ee) be2c[ot][ee] = be2[ee * 128 + o];
        }
        const float* mgb = mg + (size_t)(tok0 + 32 * mt) * 8;
        #pragma unroll
        for (int r = 0; r < 16; ++r) {
            int mrow = (r & 3) + 8 * (r >> 2) + 4 * lh;
            f32x4 g0 = *(const f32x4*)&mgb[mrow * 8];
            f32x4 g1 = *(const f32x4*)&mgb[mrow * 8 + 4];
            size_t orow = (size_t)(tok0 + 32 * mt + mrow) * 128;
            #pragma unroll
            for (int ot = 0; ot < 4; ++ot) {
                float b = bsc[ot];
                #pragma unroll
                for (int ee = 0; ee < 4; ++ee) b = fmaf(g0[ee], be2c[ot][ee], b);
                #pragma unroll
                for (int ee = 0; ee < 4; ++ee) b = fmaf(g1[ee], be2c[ot][4 + ee], b);
                float v = acc[ot][r] + Red[((mt * 4 + ot) * 16 + r) * 64 + lane] + b;
                out[orow + 32 * ot + l31] = v;
            }
        }
    }
}

// ---------------------------------------------------------------------------
extern "C" void kernel_launch(void* const* d_in, const int* in_sizes, int n_in,
                              void* d_out, int out_size, void* d_ws, size_t ws_size,
                              hipStream_t stream)
{
    const float* x   = (const float*)d_in[0];
    const float* Wr1 = (const float*)d_in[1];
    const float* br1 = (const float*)d_in[2];
    const float* Wr2 = (const float*)d_in[3];
    const float* br2 = (const float*)d_in[4];
    const float* We1 = (const float*)d_in[5];
    const float* be1 = (const float*)d_in[6];
    const float* We2 = (const float*)d_in[7];
    const float* be2 = (const float*)d_in[8];
    const float* Ws1 = (const float*)d_in[9];
    const float* bs1 = (const float*)d_in[10];
    const float* Ws2 = (const float*)d_in[11];
    const float* bs2 = (const float*)d_in[12];

    // ws: [0,368640) W1p bf16 (K=144, bias folded); [368640,696320) W2p bf16
    // (sigma-permuted); [696320, +2MB) gates fp32
    __bf16* w1p = (__bf16*)d_ws;
    __bf16* w2p = (__bf16*)((char*)d_ws + 368640);
    float*  mg  = (float*)((char*)d_ws + 696320);

    pack_kernel<<<170, 256, 0, stream>>>(We1, be1, Ws1, bs1, We2, Ws2, w1p, w2p);
    router_kernel<<<1024, 64, 0, stream>>>(x, Wr1, br1, Wr2, br2, mg);
    moe_main_kernel<<<1024, 256, 0, stream>>>(x, mg, w1p, w2p, be2, bs2,
                                              (float*)d_out);
}